// Round 2
// baseline (4001.525 us; speedup 1.0000x reference)
//
#include <hip/hip_runtime.h>

#define NN 100000
#define NE 3200000
#define IC 128
#define HD 64
#define BN_EPS 1e-5f

#define BNODES 128            // nodes per bucket (dst >> 7)
#define NB 782                // ceil(100000 / 128)

// ---------------------------------------------------------------------------
// Input projection: pre[i][c] = sum_k x[i][k] * Wp[k][c] + bp[c]
__global__ __launch_bounds__(256) void k_gemm_in(
    const float* __restrict__ x, const float* __restrict__ Wp,
    const float* __restrict__ bp, float* __restrict__ pre) {
  __shared__ float sW[IC * HD];   // 32 KB
  __shared__ float sX[4 * IC];    // 2 KB
  int tid = threadIdx.x;
  for (int i = tid; i < IC * HD; i += 256) sW[i] = Wp[i];
  int row0 = blockIdx.x * 4;
  for (int i = tid; i < 4 * IC; i += 256) sX[i] = x[(size_t)row0 * IC + i];
  __syncthreads();
  int r = tid >> 6, c = tid & 63;
  float acc = bp[c];
  const float* xr = &sX[r * IC];
#pragma unroll 8
  for (int k = 0; k < IC; ++k) acc = fmaf(xr[k], sW[k * HD + c], acc);
  pre[(size_t)(row0 + r) * HD + c] = acc;
}

// ---------------------------------------------------------------------------
// BN stats: per-channel sum / sumsq into stats[0..63] / stats[64..127].
__global__ __launch_bounds__(256) void k_bn_stats(
    const float* __restrict__ pre, float* __restrict__ stats) {
  __shared__ float ss[256], sq[256];
  int tid = threadIdx.x;
  float s = 0.f, q = 0.f;
  for (size_t i = (size_t)blockIdx.x * 256 + tid; i < (size_t)NN * HD;
       i += (size_t)gridDim.x * 256) {
    float v = pre[i];
    s += v;
    q = fmaf(v, v, q);
  }
  ss[tid] = s;
  sq[tid] = q;
  __syncthreads();
  if (tid < 64) {
    s = ss[tid] + ss[tid + 64] + ss[tid + 128] + ss[tid + 192];
    q = sq[tid] + sq[tid + 64] + sq[tid + 128] + sq[tid + 192];
    atomicAdd(&stats[tid], s);
    atomicAdd(&stats[64 + tid], q);
  }
}

// ---------------------------------------------------------------------------
// BN normalize + ReLU (+ optional residual added AFTER relu).
template <bool RESID>
__global__ __launch_bounds__(256) void k_bn_relu(
    const float* __restrict__ pre, const float* __restrict__ stats,
    const float* __restrict__ g, const float* __restrict__ b,
    const float* __restrict__ resid, float* __restrict__ out) {
  size_t i = (size_t)blockIdx.x * 256 + threadIdx.x;
  int c = threadIdx.x & 63;
  const float invN = 1.0f / NN;
  float m = stats[c] * invN;
  float v = stats[64 + c] * invN - m * m;
  float sc = g[c] * rsqrtf(v + BN_EPS);
  float val = (pre[i] - m) * sc + b[c];
  val = fmaxf(val, 0.f);
  if (RESID) val += resid[i];
  out[i] = val;
}

// ---------------------------------------------------------------------------
// Binning phase A1: bucket histogram (block-local LDS hist, then global add).
__global__ __launch_bounds__(256) void k_hist(const int* __restrict__ dst,
                                              unsigned int* __restrict__ bcnt) {
  __shared__ unsigned int h[NB];
  for (int i = threadIdx.x; i < NB; i += 256) h[i] = 0u;
  __syncthreads();
  int i0 = blockIdx.x * 256 + threadIdx.x;
  int stride = gridDim.x * 256;
  for (int e = i0; e < NE; e += stride) atomicAdd(&h[dst[e] >> 7], 1u);
  __syncthreads();
  for (int i = threadIdx.x; i < NB; i += 256)
    if (h[i]) atomicAdd(&bcnt[i], h[i]);
}

// ---------------------------------------------------------------------------
// Binning phase A2: exclusive prefix sum over NB bucket counts (one block).
__global__ __launch_bounds__(1024) void k_prefix(
    const unsigned int* __restrict__ bcnt, unsigned int* __restrict__ bstart,
    unsigned int* __restrict__ cursor) {
  __shared__ unsigned int s[1024];
  int t = threadIdx.x;
  unsigned int my = (t < NB) ? bcnt[t] : 0u;
  s[t] = my;
  __syncthreads();
  for (int off = 1; off < 1024; off <<= 1) {
    unsigned int v = (t >= off) ? s[t - off] : 0u;
    __syncthreads();
    s[t] += v;
    __syncthreads();
  }
  if (t < NB) {
    unsigned int st = s[t] - my;  // exclusive
    bstart[t] = st;
    cursor[t] = st;
  }
  if (t == NB - 1) bstart[NB] = s[t];
}

// ---------------------------------------------------------------------------
// Binning phase A3: scatter edges into buckets, packed u32 = src | (dl<<20).
__global__ __launch_bounds__(256) void k_scatter(
    const int* __restrict__ src, const int* __restrict__ dst,
    unsigned int* __restrict__ cursor, unsigned int* __restrict__ binned) {
  int i0 = blockIdx.x * 256 + threadIdx.x;
  int stride = gridDim.x * 256;
  for (int e = i0; e < NE; e += stride) {
    int d = dst[e];
    int b = d >> 7;
    unsigned int pos = atomicAdd(&cursor[b], 1u);
    binned[pos] = (unsigned int)src[e] | ((unsigned int)(d & (BNODES - 1)) << 20);
  }
}

// ---------------------------------------------------------------------------
// Aggregation with LDS accumulators: one block per bucket, wave per edge,
// lane = channel. Output is already mean-divided.
__global__ __launch_bounds__(512) void k_aggr_binned(
    const unsigned int* __restrict__ binned,
    const unsigned int* __restrict__ bstart, const float* __restrict__ h,
    float* __restrict__ aggr) {
  __shared__ float acc[BNODES * HD];  // 32 KB
  __shared__ float cl[BNODES];        // 0.5 KB
  int tid = threadIdx.x;
  for (int i = tid; i < BNODES * HD; i += 512) acc[i] = 0.f;
  for (int i = tid; i < BNODES; i += 512) cl[i] = 0.f;
  __syncthreads();
  int b = blockIdx.x;
  int e0 = (int)bstart[b], e1 = (int)bstart[b + 1];
  int lane = tid & 63, w = tid >> 6;
  for (int e = e0 + w; e < e1; e += 8) {
    unsigned int u = binned[e];
    int s = (int)(u & 0xFFFFFu);
    int dl = (int)(u >> 20);
    float v = h[(size_t)s * HD + lane];
    atomicAdd(&acc[dl * HD + lane], v);
    if (lane == 0) atomicAdd(&cl[dl], 1.f);
  }
  __syncthreads();
  int base = b * BNODES;
  // write averaged rows, float4 per thread
  for (int i = tid; i < BNODES * (HD / 4); i += 512) {
    int nl = i >> 4;          // local node
    int node = base + nl;
    if (node < NN) {
      float c = fmaxf(cl[nl], 1.f);
      float inv = 1.0f / c;
      float4 v = *(const float4*)&acc[i * 4];
      v.x *= inv; v.y *= inv; v.z *= inv; v.w *= inv;
      *(float4*)&aggr[(size_t)node * HD + (i & 15) * 4] = v;
    }
  }
}

// ---------------------------------------------------------------------------
// SAGE combine: pre[i] = aggr[i] @ Wl + bl + h[i] @ Wr   (aggr pre-averaged)
__global__ __launch_bounds__(512) void k_combine(
    const float* __restrict__ aggr, const float* __restrict__ h,
    const float* __restrict__ Wl, const float* __restrict__ bl,
    const float* __restrict__ Wr, float* __restrict__ pre) {
  __shared__ float sWl[HD * HD], sWr[HD * HD];  // 16 KB each
  __shared__ float sA[8 * HD], sH[8 * HD];      // 2 KB each
  int tid = threadIdx.x;
  for (int i = tid; i < HD * HD; i += 512) {
    sWl[i] = Wl[i];
    sWr[i] = Wr[i];
  }
  int row0 = blockIdx.x * 8;
  for (int i = tid; i < 8 * HD; i += 512) {
    sA[i] = aggr[(size_t)row0 * HD + i];
    sH[i] = h[(size_t)row0 * HD + i];
  }
  __syncthreads();
  int r = tid >> 6, c = tid & 63;
  float acc = bl[c];
  const float* ar = &sA[r * HD];
  const float* hr = &sH[r * HD];
#pragma unroll 8
  for (int k = 0; k < HD; ++k) {
    acc = fmaf(ar[k], sWl[k * HD + c], acc);
    acc = fmaf(hr[k], sWr[k * HD + c], acc);
  }
  pre[(size_t)(row0 + r) * HD + c] = acc;
}

// ---------------------------------------------------------------------------
// Output head: out[i][o] = sum_k h[i][k]*Wo[k][o] + bo[o], o in {0,1}.
__global__ __launch_bounds__(256) void k_head(
    const float* __restrict__ h, const float* __restrict__ Wo,
    const float* __restrict__ bo, float* __restrict__ out) {
  int lane = threadIdx.x & 63;
  int wid = (int)((blockIdx.x * blockDim.x + threadIdx.x) >> 6);
  int nw = (int)((gridDim.x * blockDim.x) >> 6);
  float w0 = Wo[lane * 2], w1 = Wo[lane * 2 + 1];
  float b0 = bo[0], b1 = bo[1];
  for (int row = wid; row < NN; row += nw) {
    float v = h[(size_t)row * HD + lane];
    float a0 = v * w0, a1 = v * w1;
#pragma unroll
    for (int off = 32; off > 0; off >>= 1) {
      a0 += __shfl_down(a0, off);
      a1 += __shfl_down(a1, off);
    }
    if (lane == 0) {
      out[(size_t)row * 2] = a0 + b0;
      out[(size_t)row * 2 + 1] = a1 + b1;
    }
  }
}

// ---------------------------------------------------------------------------
extern "C" void kernel_launch(void* const* d_in, const int* in_sizes, int n_in,
                              void* d_out, int out_size, void* d_ws,
                              size_t ws_size, hipStream_t stream) {
  const float* x = (const float*)d_in[0];
  const int* ei = (const int*)d_in[1];
  const float* Wp = (const float*)d_in[2];
  const float* bp = (const float*)d_in[3];
  const float* g_in = (const float*)d_in[4];
  const float* b_in = (const float*)d_in[5];
  const float* Wl0 = (const float*)d_in[6];
  const float* bl0 = (const float*)d_in[7];
  const float* Wr0 = (const float*)d_in[8];
  const float* g0 = (const float*)d_in[9];
  const float* b0 = (const float*)d_in[10];
  const float* Wl1 = (const float*)d_in[11];
  const float* bl1 = (const float*)d_in[12];
  const float* Wr1 = (const float*)d_in[13];
  const float* g1 = (const float*)d_in[14];
  const float* b1 = (const float*)d_in[15];
  const float* Wo = (const float*)d_in[16];
  const float* bo = (const float*)d_in[17];
  float* out = (float*)d_out;

  const int* src = ei;
  const int* dst = ei + NE;

  float* ws = (float*)d_ws;
  float* h0 = ws;                              // [NN*HD]
  float* pre = ws + (size_t)NN * HD;           // [NN*HD]
  float* hb = ws + (size_t)2 * NN * HD;        // [NN*HD]
  float* aggr = ws + (size_t)3 * NN * HD;      // [NN*HD]
  unsigned int* binned = (unsigned int*)(ws + (size_t)4 * NN * HD);  // [NE]
  unsigned int* bcnt = binned + NE;            // [NB]
  unsigned int* bstart = bcnt + NB;            // [NB+1]
  unsigned int* cursor = bstart + NB + 1;      // [NB]
  float* stats = (float*)(cursor + NB);        // [128]

  const int ELEM_BLOCKS = (NN * HD) / 256;  // 25000
  const int GEMM_BLOCKS = NN / 4;           // 25000
  const int COMB_BLOCKS = NN / 8;           // 12500

  // ---- input projection + BN + relu -> h0
  k_gemm_in<<<GEMM_BLOCKS, 256, 0, stream>>>(x, Wp, bp, pre);
  hipMemsetAsync(stats, 0, 128 * sizeof(float), stream);
  k_bn_stats<<<1024, 256, 0, stream>>>(pre, stats);
  k_bn_relu<false><<<ELEM_BLOCKS, 256, 0, stream>>>(pre, stats, g_in, b_in,
                                                    nullptr, h0);

  // ---- bin edges by dst bucket (shared by both layers)
  hipMemsetAsync(bcnt, 0, NB * sizeof(unsigned int), stream);
  k_hist<<<512, 256, 0, stream>>>(dst, bcnt);
  k_prefix<<<1, 1024, 0, stream>>>(bcnt, bstart, cursor);
  k_scatter<<<512, 256, 0, stream>>>(src, dst, cursor, binned);

  // ---- layer 0
  k_aggr_binned<<<NB, 512, 0, stream>>>(binned, bstart, h0, aggr);
  k_combine<<<COMB_BLOCKS, 512, 0, stream>>>(aggr, h0, Wl0, bl0, Wr0, pre);
  hipMemsetAsync(stats, 0, 128 * sizeof(float), stream);
  k_bn_stats<<<1024, 256, 0, stream>>>(pre, stats);
  k_bn_relu<false><<<ELEM_BLOCKS, 256, 0, stream>>>(pre, stats, g0, b0,
                                                    nullptr, hb);  // hb = h1

  // ---- layer 1 (residual = h0, added after relu)
  k_aggr_binned<<<NB, 512, 0, stream>>>(binned, bstart, hb, aggr);
  k_combine<<<COMB_BLOCKS, 512, 0, stream>>>(aggr, hb, Wl1, bl1, Wr1, pre);
  hipMemsetAsync(stats, 0, 128 * sizeof(float), stream);
  k_bn_stats<<<1024, 256, 0, stream>>>(pre, stats);
  k_bn_relu<true><<<ELEM_BLOCKS, 256, 0, stream>>>(pre, stats, g1, b1, h0,
                                                   hb);  // hb = h2

  // ---- output head
  k_head<<<1024, 256, 0, stream>>>(hb, Wo, bo, out);
}

// Round 3
// 1213.245 us; speedup vs baseline: 3.2982x; 3.2982x over previous
//
#include <hip/hip_runtime.h>

#define NN 100000
#define NE 3200000
#define IC 128
#define HD 64
#define BN_EPS 1e-5f
#define CHUNK 98  // ceil(NN / 1024)

// ---------------------------------------------------------------------------
// Input projection: pre[i][c] = sum_k x[i][k] * Wp[k][c] + bp[c]
__global__ __launch_bounds__(256) void k_gemm_in(
    const float* __restrict__ x, const float* __restrict__ Wp,
    const float* __restrict__ bp, float* __restrict__ pre) {
  __shared__ float sW[IC * HD];   // 32 KB
  __shared__ float sX[4 * IC];    // 2 KB
  int tid = threadIdx.x;
  for (int i = tid; i < IC * HD; i += 256) sW[i] = Wp[i];
  int row0 = blockIdx.x * 4;
  for (int i = tid; i < 4 * IC; i += 256) sX[i] = x[(size_t)row0 * IC + i];
  __syncthreads();
  int r = tid >> 6, c = tid & 63;
  float acc = bp[c];
  const float* xr = &sX[r * IC];
#pragma unroll 8
  for (int k = 0; k < IC; ++k) acc = fmaf(xr[k], sW[k * HD + c], acc);
  pre[(size_t)(row0 + r) * HD + c] = acc;
}

// ---------------------------------------------------------------------------
// BN stats: per-channel sum / sumsq into stats[0..63] / stats[64..127].
__global__ __launch_bounds__(256) void k_bn_stats(
    const float* __restrict__ pre, float* __restrict__ stats) {
  __shared__ float ss[256], sq[256];
  int tid = threadIdx.x;
  float s = 0.f, q = 0.f;
  for (size_t i = (size_t)blockIdx.x * 256 + tid; i < (size_t)NN * HD;
       i += (size_t)gridDim.x * 256) {
    float v = pre[i];
    s += v;
    q = fmaf(v, v, q);
  }
  ss[tid] = s;
  sq[tid] = q;
  __syncthreads();
  if (tid < 64) {
    s = ss[tid] + ss[tid + 64] + ss[tid + 128] + ss[tid + 192];
    q = sq[tid] + sq[tid + 64] + sq[tid + 128] + sq[tid + 192];
    atomicAdd(&stats[tid], s);
    atomicAdd(&stats[64 + tid], q);
  }
}

// ---------------------------------------------------------------------------
// BN normalize + ReLU (+ optional residual added AFTER relu).
template <bool RESID>
__global__ __launch_bounds__(256) void k_bn_relu(
    const float* __restrict__ pre, const float* __restrict__ stats,
    const float* __restrict__ g, const float* __restrict__ b,
    const float* __restrict__ resid, float* __restrict__ out) {
  size_t i = (size_t)blockIdx.x * 256 + threadIdx.x;
  int c = threadIdx.x & 63;
  const float invN = 1.0f / NN;
  float m = stats[c] * invN;
  float v = stats[64 + c] * invN - m * m;
  float sc = g[c] * rsqrtf(v + BN_EPS);
  float val = (pre[i] - m) * sc + b[c];
  val = fmaxf(val, 0.f);
  if (RESID) val += resid[i];
  out[i] = val;
}

// ---------------------------------------------------------------------------
// Sort phase 1: per-node degree histogram (global atomics, L2-resident).
__global__ __launch_bounds__(256) void k_hist(const int* __restrict__ dst,
                                              unsigned int* __restrict__ cnt) {
  int i0 = blockIdx.x * 256 + threadIdx.x;
  int stride = gridDim.x * 256;
  for (int e = i0; e < NE; e += stride) atomicAdd(&cnt[dst[e]], 1u);
}

// ---------------------------------------------------------------------------
// Sort phase 2: exclusive prefix over 100k degrees, one 1024-thread block.
// Writes cursor[] = exclusive start offsets (scatter will advance these).
__global__ __launch_bounds__(1024) void k_prefix(
    const unsigned int* __restrict__ cnt, unsigned int* __restrict__ cursor) {
  __shared__ unsigned int s[1024];
  int t = threadIdx.x;
  int base = t * CHUNK;
  unsigned int sum = 0;
  for (int i = 0; i < CHUNK; ++i) {
    int idx = base + i;
    if (idx < NN) sum += cnt[idx];
  }
  s[t] = sum;
  __syncthreads();
  for (int off = 1; off < 1024; off <<= 1) {
    unsigned int v = (t >= off) ? s[t - off] : 0u;
    __syncthreads();
    s[t] += v;
    __syncthreads();
  }
  unsigned int run = s[t] - sum;  // exclusive prefix of this chunk
  for (int i = 0; i < CHUNK; ++i) {
    int idx = base + i;
    if (idx < NN) {
      cursor[idx] = run;
      run += cnt[idx];
    }
  }
}

// ---------------------------------------------------------------------------
// Sort phase 3: scatter src into dst-sorted order.
// After this, cursor[n] == end offset of node n's segment.
__global__ __launch_bounds__(256) void k_scatter(
    const int* __restrict__ src, const int* __restrict__ dst,
    unsigned int* __restrict__ cursor, unsigned int* __restrict__ sorted_src) {
  int i0 = blockIdx.x * 256 + threadIdx.x;
  int stride = gridDim.x * 256;
  for (int e = i0; e < NE; e += stride) {
    unsigned int pos = atomicAdd(&cursor[dst[e]], 1u);
    sorted_src[pos] = (unsigned int)src[e];
  }
}

// ---------------------------------------------------------------------------
// Aggregation over sorted edges: one wave per node, lane = channel.
// No atomics; register accumulation; mean fused. cursor[n] = segment end.
__global__ __launch_bounds__(256) void k_aggr_sorted(
    const unsigned int* __restrict__ sorted_src,
    const unsigned int* __restrict__ cursor, const float* __restrict__ h,
    float* __restrict__ aggr) {
  int lane = threadIdx.x & 63;
  int n = (int)((blockIdx.x * 256 + threadIdx.x) >> 6);
  if (n >= NN) return;
  int e0 = (n == 0) ? 0 : (int)cursor[n - 1];
  int e1 = (int)cursor[n];
  float a0 = 0.f, a1 = 0.f, a2 = 0.f, a3 = 0.f;
  int e = e0;
  for (; e + 4 <= e1; e += 4) {
    unsigned int s0 = sorted_src[e];
    unsigned int s1 = sorted_src[e + 1];
    unsigned int s2 = sorted_src[e + 2];
    unsigned int s3 = sorted_src[e + 3];
    a0 += h[(size_t)s0 * HD + lane];
    a1 += h[(size_t)s1 * HD + lane];
    a2 += h[(size_t)s2 * HD + lane];
    a3 += h[(size_t)s3 * HD + lane];
  }
  for (; e < e1; ++e) a0 += h[(size_t)sorted_src[e] * HD + lane];
  float acc = (a0 + a1) + (a2 + a3);
  float cntf = (float)(e1 - e0);
  float inv = (cntf > 0.f) ? 1.0f / cntf : 0.f;
  aggr[(size_t)n * HD + lane] = acc * inv;
}

// ---------------------------------------------------------------------------
// SAGE combine: pre[i] = aggr[i] @ Wl + bl + h[i] @ Wr  (aggr pre-averaged).
// Safe to call with pre == aggr: each block stages its own rows to LDS
// (then __syncthreads) before overwriting them.
__global__ __launch_bounds__(512) void k_combine(
    const float* __restrict__ aggr, const float* __restrict__ h,
    const float* __restrict__ Wl, const float* __restrict__ bl,
    const float* __restrict__ Wr, float* __restrict__ pre) {
  __shared__ float sWl[HD * HD], sWr[HD * HD];  // 16 KB each
  __shared__ float sA[8 * HD], sH[8 * HD];      // 2 KB each
  int tid = threadIdx.x;
  for (int i = tid; i < HD * HD; i += 512) {
    sWl[i] = Wl[i];
    sWr[i] = Wr[i];
  }
  int row0 = blockIdx.x * 8;
  for (int i = tid; i < 8 * HD; i += 512) {
    sA[i] = aggr[(size_t)row0 * HD + i];
    sH[i] = h[(size_t)row0 * HD + i];
  }
  __syncthreads();
  int r = tid >> 6, c = tid & 63;
  float acc = bl[c];
  const float* ar = &sA[r * HD];
  const float* hr = &sH[r * HD];
#pragma unroll 8
  for (int k = 0; k < HD; ++k) {
    acc = fmaf(ar[k], sWl[k * HD + c], acc);
    acc = fmaf(hr[k], sWr[k * HD + c], acc);
  }
  pre[(size_t)(row0 + r) * HD + c] = acc;
}

// ---------------------------------------------------------------------------
// Output head: out[i][o] = sum_k h[i][k]*Wo[k][o] + bo[o], o in {0,1}.
__global__ __launch_bounds__(256) void k_head(
    const float* __restrict__ h, const float* __restrict__ Wo,
    const float* __restrict__ bo, float* __restrict__ out) {
  int lane = threadIdx.x & 63;
  int wid = (int)((blockIdx.x * blockDim.x + threadIdx.x) >> 6);
  int nw = (int)((gridDim.x * blockDim.x) >> 6);
  float w0 = Wo[lane * 2], w1 = Wo[lane * 2 + 1];
  float b0 = bo[0], b1 = bo[1];
  for (int row = wid; row < NN; row += nw) {
    float v = h[(size_t)row * HD + lane];
    float a0 = v * w0, a1 = v * w1;
#pragma unroll
    for (int off = 32; off > 0; off >>= 1) {
      a0 += __shfl_down(a0, off);
      a1 += __shfl_down(a1, off);
    }
    if (lane == 0) {
      out[(size_t)row * 2] = a0 + b0;
      out[(size_t)row * 2 + 1] = a1 + b1;
    }
  }
}

// ---------------------------------------------------------------------------
extern "C" void kernel_launch(void* const* d_in, const int* in_sizes, int n_in,
                              void* d_out, int out_size, void* d_ws,
                              size_t ws_size, hipStream_t stream) {
  const float* x = (const float*)d_in[0];
  const int* ei = (const int*)d_in[1];
  const float* Wp = (const float*)d_in[2];
  const float* bp = (const float*)d_in[3];
  const float* g_in = (const float*)d_in[4];
  const float* b_in = (const float*)d_in[5];
  const float* Wl0 = (const float*)d_in[6];
  const float* bl0 = (const float*)d_in[7];
  const float* Wr0 = (const float*)d_in[8];
  const float* g0 = (const float*)d_in[9];
  const float* b0 = (const float*)d_in[10];
  const float* Wl1 = (const float*)d_in[11];
  const float* bl1 = (const float*)d_in[12];
  const float* Wr1 = (const float*)d_in[13];
  const float* g1 = (const float*)d_in[14];
  const float* b1 = (const float*)d_in[15];
  const float* Wo = (const float*)d_in[16];
  const float* bo = (const float*)d_in[17];
  float* out = (float*)d_out;

  const int* src = ei;
  const int* dst = ei + NE;

  float* ws = (float*)d_ws;
  float* h0 = ws;                          // [NN*HD]  bufA
  float* hb = ws + (size_t)NN * HD;        // [NN*HD]  bufB
  float* pre = ws + (size_t)2 * NN * HD;   // [NN*HD]  bufC (pre == aggr)
  unsigned int* sorted_src = (unsigned int*)(ws + (size_t)3 * NN * HD);  // [NE]
  unsigned int* cnt = sorted_src + NE;     // [NN]
  unsigned int* cursor = cnt + NN;         // [NN]
  float* stats = (float*)(cursor + NN);    // [128]

  const int ELEM_BLOCKS = (NN * HD) / 256;  // 25000
  const int GEMM_BLOCKS = NN / 4;           // 25000
  const int COMB_BLOCKS = NN / 8;           // 12500
  const int AGGR_BLOCKS = 25000;            // 100k waves, 4/block

  // ---- input projection + BN + relu -> h0
  k_gemm_in<<<GEMM_BLOCKS, 256, 0, stream>>>(x, Wp, bp, pre);
  hipMemsetAsync(stats, 0, 128 * sizeof(float), stream);
  k_bn_stats<<<1024, 256, 0, stream>>>(pre, stats);
  k_bn_relu<false><<<ELEM_BLOCKS, 256, 0, stream>>>(pre, stats, g_in, b_in,
                                                    nullptr, h0);

  // ---- counting-sort edges by dst (shared by both layers)
  hipMemsetAsync(cnt, 0, NN * sizeof(unsigned int), stream);
  k_hist<<<2048, 256, 0, stream>>>(dst, cnt);
  k_prefix<<<1, 1024, 0, stream>>>(cnt, cursor);
  k_scatter<<<2048, 256, 0, stream>>>(src, dst, cursor, sorted_src);
  // after scatter: cursor[n] == end offset of node n's segment

  // ---- layer 0
  k_aggr_sorted<<<AGGR_BLOCKS, 256, 0, stream>>>(sorted_src, cursor, h0, pre);
  k_combine<<<COMB_BLOCKS, 512, 0, stream>>>(pre, h0, Wl0, bl0, Wr0, pre);
  hipMemsetAsync(stats, 0, 128 * sizeof(float), stream);
  k_bn_stats<<<1024, 256, 0, stream>>>(pre, stats);
  k_bn_relu<false><<<ELEM_BLOCKS, 256, 0, stream>>>(pre, stats, g0, b0,
                                                    nullptr, hb);  // hb = h1

  // ---- layer 1 (residual = h0, added after relu)
  k_aggr_sorted<<<AGGR_BLOCKS, 256, 0, stream>>>(sorted_src, cursor, hb, pre);
  k_combine<<<COMB_BLOCKS, 512, 0, stream>>>(pre, hb, Wl1, bl1, Wr1, pre);
  hipMemsetAsync(stats, 0, 128 * sizeof(float), stream);
  k_bn_stats<<<1024, 256, 0, stream>>>(pre, stats);
  k_bn_relu<true><<<ELEM_BLOCKS, 256, 0, stream>>>(pre, stats, g1, b1, h0,
                                                   hb);  // hb = h2

  // ---- output head
  k_head<<<1024, 256, 0, stream>>>(hb, Wo, bo, out);
}